// Round 16
// baseline (200.771 us; speedup 1.0000x reference)
//
#include <hip/hip_runtime.h>
#include <math.h>

#define DF 128
#define NPB 256    // nodes per bucket (partition path)
#define EPB 4096   // edges per hist block (prep)
#define EPBA 2048  // edges per passA block
#define CAP 7168   // passB LDS image capacity (edges)

typedef __attribute__((ext_vector_type(8))) short bf16x8;
typedef __attribute__((ext_vector_type(4))) float f32x4;

__device__ __forceinline__ float bf2f(uint u) {
    union { uint i; float f; } v; v.i = u << 16; return v.f;
}
__device__ __forceinline__ uint f2bf(float f) {  // round-to-nearest-even
    union { float f; uint i; } v; v.f = f;
    return (v.i + 0x7fffu + ((v.i >> 16) & 1u)) >> 16;
}

// ---- fused prep: cvt_x (float4) + cvtW + per-block bucket hist ----

__global__ void prep_k(const float* __restrict__ x, uint* __restrict__ xb, int n4,
                       const float* __restrict__ W1, const float* __restrict__ W2,
                       uint* __restrict__ Wt1, uint* __restrict__ Wt2,
                       const int* __restrict__ dst, int* __restrict__ bhist, int E,
                       int cvtxB) {
    __shared__ int lh[256];
    int b = blockIdx.x;
    int t = threadIdx.x;
    if (b < cvtxB) {
        int i = b * 256 + t;
        if (i < n4) {
            float4 v = ((const float4*)x)[i];
            uint2 o;
            o.x = f2bf(v.x) | (f2bf(v.y) << 16);
            o.y = f2bf(v.z) | (f2bf(v.w) << 16);
            ((uint2*)xb)[i] = o;
        }
    } else if (b < cvtxB + 64) {
        int i = (b - cvtxB) * 256 + t;  // 0..16383
        const float* W = (i < 8192) ? W1 : W2;
        uint* Wt = (i < 8192) ? Wt1 : Wt2;
        int j = i & 8191;
        int n = j >> 6, kk = j & 63;
        Wt[n * 64 + kk] = f2bf(W[(2 * kk) * DF + n]) | (f2bf(W[(2 * kk + 1) * DF + n]) << 16);
    } else {
        int hb = b - cvtxB - 64;
        int base = hb * EPB;
        lh[t] = 0;
        __syncthreads();
#pragma unroll
        for (int k = 0; k < EPB / 256; ++k) {
            int i = base + k * 256 + t;
            if (i < E) atomicAdd(&lh[dst[i] >> 8], 1);
        }
        __syncthreads();
        bhist[hb * 256 + t] = lh[t];
    }
}

// single block: reduce per-block hists + exclusive scan -> bkoff[257], init gcur
__global__ void bscan_k(const int* __restrict__ bhist, int histB,
                        int* __restrict__ bkoff, int* __restrict__ gcur) {
    int t = threadIdx.x;
    int v = 0;
#pragma unroll 4
    for (int hb = 0; hb < histB; ++hb) v += bhist[hb * 256 + t];
    __shared__ int sm[256];
    sm[t] = v;
    __syncthreads();
    for (int off = 1; off < 256; off <<= 1) {
        int u = (t >= off) ? sm[t - off] : 0;
        __syncthreads();
        sm[t] += u;
        __syncthreads();
    }
    int ex = sm[t] - v;
    bkoff[t] = ex;
    gcur[t] = ex;
    if (t == 255) bkoff[256] = sm[255];
}

// ---------------- partitioned CSR fill ----------------

__global__ __launch_bounds__(256) void passA_k(
    const int* __restrict__ src, const int* __restrict__ dst,
    const float* __restrict__ ew, int* __restrict__ gcur,
    uint2* __restrict__ stage, int E) {
    __shared__ int lhist[256];
    __shared__ int lscan[256];
    __shared__ int lcur[256];
    __shared__ int gbase[256];
    __shared__ int lbk[EPBA];
    __shared__ uint2 img[EPBA];
    int t = threadIdx.x;
    int base = blockIdx.x * EPBA;
    int cnt = min(EPBA, E - base);
    lhist[t] = 0;
    __syncthreads();
    uint ps[EPBA / 256], pw[EPBA / 256];
    int pb[EPBA / 256];
#pragma unroll
    for (int k = 0; k < EPBA / 256; ++k) {
        int i = base + k * 256 + t;
        pb[k] = -1;
        if (i < E) {
            int d = dst[i];
            int bk = d >> 8;  // NPB=256
            pb[k] = bk;
            ps[k] = (uint)src[i] | ((uint)(d & 255) << 23);
            pw[k] = __float_as_uint(ew[i]);
            atomicAdd(&lhist[bk], 1);
        }
    }
    __syncthreads();
    int v = lhist[t];
    lscan[t] = v;
    __syncthreads();
    for (int off = 1; off < 256; off <<= 1) {
        int u = (t >= off) ? lscan[t - off] : 0;
        __syncthreads();
        lscan[t] += u;
        __syncthreads();
    }
    lcur[t] = lscan[t] - v;
    if (v > 0) gbase[t] = atomicAdd(&gcur[t], v);
    __syncthreads();
#pragma unroll
    for (int k = 0; k < EPBA / 256; ++k) {
        if (pb[k] >= 0) {
            int p = atomicAdd(&lcur[pb[k]], 1);
            img[p] = make_uint2(ps[k], pw[k]);
            lbk[p] = pb[k];
        }
    }
    __syncthreads();
    for (int i = t; i < cnt; i += 256) {
        int bk = lbk[i];
        stage[gbase[bk] + (i - (lscan[bk] - lhist[bk]))] = img[i];
    }
}

__global__ __launch_bounds__(256) void passB_k(
    const uint2* __restrict__ stage, const int* __restrict__ bkoff,
    int* __restrict__ rowptr, int* __restrict__ cursor,
    int2* __restrict__ adj, int N, int nbk) {
    __shared__ int lhist[256];
    __shared__ int lpre[256];
    __shared__ int lcur[256];
    __shared__ uint2 img[CAP];
    int t = threadIdx.x;
    int b = blockIdx.x;
    int nb0 = b * NPB;
    int nn = min(NPB, N - nb0);
    int ebase = bkoff[b];
    int ecnt = bkoff[b + 1] - ebase;
    lhist[t] = 0;
    __syncthreads();
    for (int i = t; i < ecnt; i += 256) {
        uint2 e = stage[ebase + i];
        atomicAdd(&lhist[(e.x >> 23) & 255], 1);
    }
    __syncthreads();
    int v = lhist[t];
    lpre[t] = v;
    __syncthreads();
    for (int off = 1; off < 256; off <<= 1) {
        int u = (t >= off) ? lpre[t - off] : 0;
        __syncthreads();
        lpre[t] += u;
        __syncthreads();
    }
    int myoff = lpre[t] - v;
    lcur[t] = myoff;
    if (t < nn) {
        rowptr[nb0 + t] = ebase + myoff;
        cursor[nb0 + t] = ebase + myoff;
    }
    if (b == nbk - 1 && t == 0) rowptr[N] = ebase + ecnt;
    __syncthreads();
    if (ecnt <= CAP) {
        for (int i = t; i < ecnt; i += 256) {
            uint2 e = stage[ebase + i];
            int p = atomicAdd(&lcur[(e.x >> 23) & 255], 1);
            img[p] = make_uint2(e.x & 0x7fffffu, e.y);
        }
        __syncthreads();
        for (int i = t; i < ecnt; i += 256) {
            uint2 e = img[i];
            adj[ebase + i] = make_int2((int)e.x, (int)e.y);
        }
    } else {
        for (int i = t; i < ecnt; i += 256) {
            uint2 e = stage[ebase + i];
            int dl = (e.x >> 23) & 255;
            int p = atomicAdd(&cursor[nb0 + dl], 1);
            adj[p] = make_int2((int)(e.x & 0x7fffffu), (int)e.y);
        }
    }
}

// ---------------- generic fallback path (N > 65536 only) ----------------

__global__ void histn_k(const int* __restrict__ dst, int* __restrict__ cnt, int E) {
    int i = blockIdx.x * blockDim.x + threadIdx.x;
    if (i < E) atomicAdd(&cnt[dst[i]], 1);
}

__global__ void partial_k(const int* __restrict__ cnt, int* __restrict__ bsum, int N) {
    int t = threadIdx.x, b = blockIdx.x;
    int base = b * 1024 + t * 4;
    int s = 0;
    if (base + 4 <= N) {
        int4 v = *(const int4*)(cnt + base);
        s = v.x + v.y + v.z + v.w;
    } else {
        for (int j = 0; j < 4; ++j)
            if (base + j < N) s += cnt[base + j];
    }
    __shared__ int sm[256];
    sm[t] = s;
    __syncthreads();
    for (int off = 128; off > 0; off >>= 1) {
        if (t < off) sm[t] += sm[t + off];
        __syncthreads();
    }
    if (t == 0) bsum[b] = sm[0];
}

__global__ void scanb_k(const int* __restrict__ bsum, int* __restrict__ boff,
                        int* __restrict__ rowptr, int nb, int N) {
    int t = threadIdx.x;
    int v = (t < nb) ? bsum[t] : 0;
    __shared__ int sm[256];
    sm[t] = v;
    __syncthreads();
    for (int off = 1; off < 256; off <<= 1) {
        int u = (t >= off) ? sm[t - off] : 0;
        __syncthreads();
        sm[t] += u;
        __syncthreads();
    }
    if (t < nb) boff[t] = sm[t] - v;
    if (t == 255) rowptr[N] = sm[255];
}

__global__ void rowfill_k(const int* __restrict__ cnt, const int* __restrict__ boff,
                          int* __restrict__ rowptr, int* __restrict__ cursor, int N) {
    int t = threadIdx.x, b = blockIdx.x;
    int base = b * 1024 + t * 4;
    int c0 = 0, c1 = 0, c2 = 0, c3 = 0;
    if (base + 4 <= N) {
        int4 v = *(const int4*)(cnt + base);
        c0 = v.x; c1 = v.y; c2 = v.z; c3 = v.w;
    } else {
        if (base + 0 < N) c0 = cnt[base + 0];
        if (base + 1 < N) c1 = cnt[base + 1];
        if (base + 2 < N) c2 = cnt[base + 2];
        if (base + 3 < N) c3 = cnt[base + 3];
    }
    int s = c0 + c1 + c2 + c3;
    __shared__ int sm[256];
    sm[t] = s;
    __syncthreads();
    for (int off = 1; off < 256; off <<= 1) {
        int u = (t >= off) ? sm[t - off] : 0;
        __syncthreads();
        sm[t] += u;
        __syncthreads();
    }
    int run = boff[b] + sm[t] - s;
    if (base + 0 < N) { rowptr[base + 0] = run; cursor[base + 0] = run; run += c0; }
    if (base + 1 < N) { rowptr[base + 1] = run; cursor[base + 1] = run; run += c1; }
    if (base + 2 < N) { rowptr[base + 2] = run; cursor[base + 2] = run; run += c2; }
    if (base + 3 < N) { rowptr[base + 3] = run; cursor[base + 3] = run; run += c3; }
}

__global__ void fill_k(const int* __restrict__ src, const int* __restrict__ dst,
                       const float* __restrict__ ew, int* __restrict__ cursor,
                       int2* __restrict__ adj, int E) {
    int i = blockIdx.x * blockDim.x + threadIdx.x;
    if (i < E) {
        int p = atomicAdd(&cursor[dst[i]], 1);
        int2 e;
        e.x = src[i];
        e.y = __float_as_int(ew[i]);
        adj[p] = e;
    }
}

// ---- fused aggregation + MFMA: one block per 16-row strip ----
// Phase 1 (4 waves): wave processes node PAIRS concurrently (2x gather MLP:
//   8 independent uint4 row-loads in flight/lane). Edge (sidx,w) comes from a
//   broadcast load (16 lanes of a group read the same adj entry) instead of
//   shfl. Self-term (layer 2) loaded by g==0 only (group butterfly sums 4
//   groups). Mean'd bf16 rows staged in LDS (pad-136: <=2-way bank alias).
// Phase 2 (wave 0): MFMA A-frags from LDS, B from Wt; epilogue per layer.

__device__ __forceinline__ float gelu_exact(float v) {
    return 0.5f * v * (1.0f + erff(v * 0.70710678118654752440f));
}

template <int SELF>  // 0: layer1 -> bf16 out ; 1: layer2 (+residual+LN+GELU) -> f32 out
__global__ __launch_bounds__(256) void aggmm_k(
    const uint4* __restrict__ xin4, const int* __restrict__ rowptr,
    const int2* __restrict__ adj, const ushort* __restrict__ Wt,
    const float* __restrict__ bl, const float* __restrict__ gamma,
    const float* __restrict__ beta, ushort* __restrict__ outb,
    float* __restrict__ outf, int N) {
    __shared__ __align__(16) ushort rows[16][136];
    __shared__ float wbs[16];
    int t = threadIdx.x;
    int wv = t >> 6;
    int lane = t & 63;
    int row0 = blockIdx.x << 4;
    int g = lane >> 4, c = lane & 15;

#define FMA8(ACC, V, W)                                                           \
    do {                                                                          \
        ACC[0] += (W) * bf2f((V).x & 0xffffu); ACC[1] += (W) * bf2f((V).x >> 16); \
        ACC[2] += (W) * bf2f((V).y & 0xffffu); ACC[3] += (W) * bf2f((V).y >> 16); \
        ACC[4] += (W) * bf2f((V).z & 0xffffu); ACC[5] += (W) * bf2f((V).z >> 16); \
        ACC[6] += (W) * bf2f((V).w & 0xffffu); ACC[7] += (W) * bf2f((V).w >> 16); \
    } while (0)

#pragma unroll
    for (int qp = 0; qp < 2; ++qp) {  // node pairs: (wv+4qp*2... ) -> slots
        int iA = wv + qp * 8;       // node slots: wv+0/8 and wv+4/12
        int iB = wv + qp * 8 + 4;
        int nodeA = row0 + iA, nodeB = row0 + iB;
        float accA[8] = {0.f, 0.f, 0.f, 0.f, 0.f, 0.f, 0.f, 0.f};
        float accB[8] = {0.f, 0.f, 0.f, 0.f, 0.f, 0.f, 0.f, 0.f};
        float wsA = 0.f, wsB = 0.f;
        int loA = 0, hiA = 0, loB = 0, hiB = 0;
        if (nodeA < N) { loA = rowptr[nodeA]; hiA = rowptr[nodeA + 1]; }
        if (nodeB < N) { loB = rowptr[nodeB]; hiB = rowptr[nodeB + 1]; }
        if (SELF && g == 0) {  // self-loop once (butterfly sums 4 groups)
            if (nodeA < N) {
                uint4 v = xin4[(size_t)nodeA * 16 + c];
                FMA8(accA, v, 1.0f);
            }
            if (nodeB < N) {
                uint4 v = xin4[(size_t)nodeB * 16 + c];
                FMA8(accB, v, 1.0f);
            }
        }
        int nA = hiA - loA, nB = hiB - loB;
        int mx = max(nA, nB);
        for (int j = 0; j < mx; j += 16) {
            // broadcast adj loads: 4 slots per node, group g covers edges j+4k+g
            int sA[4], sB[4];
            float wA[4], wB[4];
#pragma unroll
            for (int k = 0; k < 4; ++k) {
                int eA = loA + j + 4 * k + g;
                int2 edA = (eA < hiA) ? adj[eA] : make_int2(0, 0);
                sA[k] = edA.x; wA[k] = __int_as_float(edA.y); wsA += wA[k];
                int eB = loB + j + 4 * k + g;
                int2 edB = (eB < hiB) ? adj[eB] : make_int2(0, 0);
                sB[k] = edB.x; wB[k] = __int_as_float(edB.y); wsB += wB[k];
            }
            uint4 vA[4], vB[4];
#pragma unroll
            for (int k = 0; k < 4; ++k) vA[k] = xin4[(size_t)sA[k] * 16 + c];
#pragma unroll
            for (int k = 0; k < 4; ++k) vB[k] = xin4[(size_t)sB[k] * 16 + c];
#pragma unroll
            for (int k = 0; k < 4; ++k) FMA8(accA, vA[k], wA[k]);
#pragma unroll
            for (int k = 0; k < 4; ++k) FMA8(accB, vB[k], wB[k]);
        }
        // combine 4 edge-slot groups (ws identical within group -> same butterfly)
#pragma unroll
        for (int e = 0; e < 8; ++e) {
            accA[e] += __shfl_xor(accA[e], 16); accA[e] += __shfl_xor(accA[e], 32);
            accB[e] += __shfl_xor(accB[e], 16); accB[e] += __shfl_xor(accB[e], 32);
        }
        wsA += __shfl_xor(wsA, 16); wsA += __shfl_xor(wsA, 32);
        wsB += __shfl_xor(wsB, 16); wsB += __shfl_xor(wsB, 32);
        float invA, wbA, invB, wbB;
        if (SELF) {
            invA = 1.0f / (float)(nA + 1); wbA = (wsA + 1.0f) * invA;
            invB = 1.0f / (float)(nB + 1); wbB = (wsB + 1.0f) * invB;
        } else {
            float dA = fmaxf((float)nA, 1.0f), dB = fmaxf((float)nB, 1.0f);
            invA = 1.0f / dA; wbA = wsA * invA;
            invB = 1.0f / dB; wbB = wsB * invB;
        }
        if (g == 0) {
            uint4 oA, oB;
            oA.x = f2bf(accA[0] * invA) | (f2bf(accA[1] * invA) << 16);
            oA.y = f2bf(accA[2] * invA) | (f2bf(accA[3] * invA) << 16);
            oA.z = f2bf(accA[4] * invA) | (f2bf(accA[5] * invA) << 16);
            oA.w = f2bf(accA[6] * invA) | (f2bf(accA[7] * invA) << 16);
            *reinterpret_cast<uint4*>(&rows[iA][c * 8]) = oA;
            oB.x = f2bf(accB[0] * invB) | (f2bf(accB[1] * invB) << 16);
            oB.y = f2bf(accB[2] * invB) | (f2bf(accB[3] * invB) << 16);
            oB.z = f2bf(accB[4] * invB) | (f2bf(accB[5] * invB) << 16);
            oB.w = f2bf(accB[6] * invB) | (f2bf(accB[7] * invB) << 16);
            *reinterpret_cast<uint4*>(&rows[iB][c * 8]) = oB;
            if (c == 0) { wbs[iA] = wbA; wbs[iB] = wbB; }
        }
    }
#undef FMA8
    __syncthreads();
    if (wv != 0) return;

    // wave 0: MFMA over the strip
    int kg = g << 3;
    bf16x8 af[4];
#pragma unroll
    for (int kc = 0; kc < 4; ++kc)
        af[kc] = *(const bf16x8*)&rows[c][kc * 32 + kg];

    f32x4 acc[8];
#pragma unroll
    for (int nt = 0; nt < 8; ++nt) {
        f32x4 a = {0.f, 0.f, 0.f, 0.f};
#pragma unroll
        for (int kc = 0; kc < 4; ++kc) {
            bf16x8 bf = *(const bf16x8*)(Wt + (size_t)(nt * 16 + c) * DF + kc * 32 + kg);
            a = __builtin_amdgcn_mfma_f32_16x16x32_bf16(af[kc], bf, a, 0, 0, 0);
        }
        acc[nt] = a;
    }

    const ushort* xin_s = (const ushort*)xin4;
#pragma unroll
    for (int r = 0; r < 4; ++r) {
        int i = g * 4 + r;
        int R = row0 + i;
        if (R >= N) continue;
        float wb = wbs[i];
        if (!SELF) {
#pragma unroll
            for (int nt = 0; nt < 8; ++nt) {
                int col = nt * 16 + c;
                outb[(size_t)R * DF + col] = (ushort)f2bf(acc[nt][r] + bl[col] * wb);
            }
        } else {
            float pre[8];
            float s = 0.f;
#pragma unroll
            for (int nt = 0; nt < 8; ++nt) {
                int col = nt * 16 + c;
                pre[nt] = acc[nt][r] + bl[col] * wb + bf2f(xin_s[(size_t)R * DF + col]);
                s += pre[nt];
            }
            s += __shfl_xor(s, 1);
            s += __shfl_xor(s, 2);
            s += __shfl_xor(s, 4);
            s += __shfl_xor(s, 8);
            float mu = s * (1.0f / 128.0f);
            float vs = 0.f;
#pragma unroll
            for (int nt = 0; nt < 8; ++nt) {
                float d = pre[nt] - mu;
                vs += d * d;
            }
            vs += __shfl_xor(vs, 1);
            vs += __shfl_xor(vs, 2);
            vs += __shfl_xor(vs, 4);
            vs += __shfl_xor(vs, 8);
            float rstd = rsqrtf(vs * (1.0f / 128.0f) + 1e-5f);
#pragma unroll
            for (int nt = 0; nt < 8; ++nt) {
                int col = nt * 16 + c;
                float y = (pre[nt] - mu) * rstd * gamma[col] + beta[col];
                outf[(size_t)R * DF + col] = gelu_exact(y);
            }
        }
    }
}

// ---------------- launch ----------------

extern "C" void kernel_launch(void* const* d_in, const int* in_sizes, int n_in,
                              void* d_out, int out_size, void* d_ws, size_t ws_size,
                              hipStream_t stream) {
    const float* x     = (const float*)d_in[0];
    const int*   ei    = (const int*)d_in[1];
    const float* ew    = (const float*)d_in[2];
    const float* Wl1   = (const float*)d_in[3];
    const float* bl1   = (const float*)d_in[4];
    const float* Wl2   = (const float*)d_in[5];
    const float* bl2   = (const float*)d_in[6];
    const float* gamma = (const float*)d_in[7];
    const float* beta  = (const float*)d_in[8];
    float* out = (float*)d_out;

    int N = in_sizes[0] / DF;
    int E = in_sizes[2];
    const int* src = ei;
    const int* dst = ei + E;

    char* ws = (char*)d_ws;
    size_t off = 0;
    auto alloc = [&](size_t bytes) -> void* {
        void* p = ws + off;
        off += (bytes + 255) & ~(size_t)255;
        return p;
    };
    int histB = (E + EPB - 1) / EPB;
    int*    rowptr  = (int*)alloc((size_t)(N + 1) * 4);
    int*    cursor  = (int*)alloc((size_t)N * 4);
    int*    bhist   = (int*)alloc((size_t)histB * 256 * 4);
    int*    bkoff   = (int*)alloc(1040);
    int*    gcur    = (int*)alloc(1024);
    int*    bsum    = (int*)alloc(1024);
    int*    boff    = (int*)alloc(1024);
    int2*   adj     = (int2*)alloc((size_t)E * 8);
    uint2*  stage   = (uint2*)alloc((size_t)E * 8);
    uint*   xb      = (uint*)alloc((size_t)N * DF * 2);
    ushort* x1b     = (ushort*)alloc((size_t)N * DF * 2);
    uint*   Wt1     = (uint*)alloc((size_t)DF * DF * 2);
    uint*   Wt2     = (uint*)alloc((size_t)DF * DF * 2);
    int*    cnt     = (int*)alloc((size_t)N * 4);  // fallback path only

    int nbk = (N + NPB - 1) / NPB;
    int n4 = N * DF / 4;
    int cvtxB = (n4 + 255) / 256;

    if (nbk <= 256) {
        hipLaunchKernelGGL(prep_k, dim3(cvtxB + 64 + histB), dim3(256), 0, stream,
                           x, xb, n4, Wl1, Wl2, Wt1, Wt2, dst, bhist, E, cvtxB);
        hipLaunchKernelGGL(bscan_k, dim3(1), dim3(256), 0, stream, bhist, histB, bkoff, gcur);
        int aB = (E + EPBA - 1) / EPBA;
        hipLaunchKernelGGL(passA_k, dim3(aB), dim3(256), 0, stream, src, dst, ew, gcur, stage, E);
        hipLaunchKernelGGL(passB_k, dim3(nbk), dim3(256), 0, stream,
                           stage, bkoff, rowptr, cursor, adj, N, nbk);
    } else {  // generic fallback (not taken for this problem size)
        hipMemsetAsync(cnt, 0, (size_t)N * 4, stream);
        hipLaunchKernelGGL(prep_k, dim3(cvtxB + 64), dim3(256), 0, stream,
                           x, xb, n4, Wl1, Wl2, Wt1, Wt2, dst, bhist, 0, cvtxB);
        int eb = (E + 255) / 256;
        hipLaunchKernelGGL(histn_k, dim3(eb), dim3(256), 0, stream, dst, cnt, E);
        int nb_scan = (N + 1023) / 1024;
        hipLaunchKernelGGL(partial_k, dim3(nb_scan), dim3(256), 0, stream, cnt, bsum, N);
        hipLaunchKernelGGL(scanb_k, dim3(1), dim3(256), 0, stream, bsum, boff, rowptr, nb_scan, N);
        hipLaunchKernelGGL(rowfill_k, dim3(nb_scan), dim3(256), 0, stream, cnt, boff, rowptr, cursor, N);
        hipLaunchKernelGGL(fill_k, dim3(eb), dim3(256), 0, stream, src, dst, ew, cursor, adj, E);
    }

    int nstrips = (N + 15) / 16;
    hipLaunchKernelGGL(aggmm_k<0>, dim3(nstrips), dim3(256), 0, stream,
                       (const uint4*)xb, rowptr, adj, (const ushort*)Wt1, bl1,
                       gamma, beta, x1b, (float*)nullptr, N);
    hipLaunchKernelGGL(aggmm_k<1>, dim3(nstrips), dim3(256), 0, stream,
                       (const uint4*)x1b, rowptr, adj, (const ushort*)Wt2, bl2,
                       gamma, beta, (ushort*)nullptr, out, N);
}

// Round 17
// 168.147 us; speedup vs baseline: 1.1940x; 1.1940x over previous
//
#include <hip/hip_runtime.h>
#include <math.h>

#define DF 128
#define NPB 256    // nodes per bucket (partition path)
#define EPB 4096   // edges per hist block (prep)
#define EPBA 2048  // edges per passA block
#define CAP 7168   // passB LDS image capacity (edges)

typedef __attribute__((ext_vector_type(8))) short bf16x8;
typedef __attribute__((ext_vector_type(4))) float f32x4;

__device__ __forceinline__ float bf2f(uint u) {
    union { uint i; float f; } v; v.i = u << 16; return v.f;
}
__device__ __forceinline__ uint f2bf(float f) {  // round-to-nearest-even
    union { float f; uint i; } v; v.f = f;
    return (v.i + 0x7fffu + ((v.i >> 16) & 1u)) >> 16;
}

// ---- fused prep: cvt_x (float4) + cvtW + per-block bucket hist ----

__global__ void prep_k(const float* __restrict__ x, uint* __restrict__ xb, int n4,
                       const float* __restrict__ W1, const float* __restrict__ W2,
                       uint* __restrict__ Wt1, uint* __restrict__ Wt2,
                       const int* __restrict__ dst, int* __restrict__ bhist, int E,
                       int cvtxB) {
    __shared__ int lh[256];
    int b = blockIdx.x;
    int t = threadIdx.x;
    if (b < cvtxB) {
        int i = b * 256 + t;
        if (i < n4) {
            float4 v = ((const float4*)x)[i];
            uint2 o;
            o.x = f2bf(v.x) | (f2bf(v.y) << 16);
            o.y = f2bf(v.z) | (f2bf(v.w) << 16);
            ((uint2*)xb)[i] = o;
        }
    } else if (b < cvtxB + 64) {
        int i = (b - cvtxB) * 256 + t;  // 0..16383
        const float* W = (i < 8192) ? W1 : W2;
        uint* Wt = (i < 8192) ? Wt1 : Wt2;
        int j = i & 8191;
        int n = j >> 6, kk = j & 63;
        Wt[n * 64 + kk] = f2bf(W[(2 * kk) * DF + n]) | (f2bf(W[(2 * kk + 1) * DF + n]) << 16);
    } else {
        int hb = b - cvtxB - 64;
        int base = hb * EPB;
        lh[t] = 0;
        __syncthreads();
#pragma unroll
        for (int k = 0; k < EPB / 256; ++k) {
            int i = base + k * 256 + t;
            if (i < E) atomicAdd(&lh[dst[i] >> 8], 1);
        }
        __syncthreads();
        bhist[hb * 256 + t] = lh[t];
    }
}

// single block: reduce per-block hists + exclusive scan -> bkoff[257], init gcur
__global__ void bscan_k(const int* __restrict__ bhist, int histB,
                        int* __restrict__ bkoff, int* __restrict__ gcur) {
    int t = threadIdx.x;
    int v = 0;
#pragma unroll 4
    for (int hb = 0; hb < histB; ++hb) v += bhist[hb * 256 + t];
    __shared__ int sm[256];
    sm[t] = v;
    __syncthreads();
    for (int off = 1; off < 256; off <<= 1) {
        int u = (t >= off) ? sm[t - off] : 0;
        __syncthreads();
        sm[t] += u;
        __syncthreads();
    }
    int ex = sm[t] - v;
    bkoff[t] = ex;
    gcur[t] = ex;
    if (t == 255) bkoff[256] = sm[255];
}

// ---------------- partitioned CSR fill ----------------

__global__ __launch_bounds__(256) void passA_k(
    const int* __restrict__ src, const int* __restrict__ dst,
    const float* __restrict__ ew, int* __restrict__ gcur,
    uint2* __restrict__ stage, int E) {
    __shared__ int lhist[256];
    __shared__ int lscan[256];
    __shared__ int lcur[256];
    __shared__ int gbase[256];
    __shared__ int lbk[EPBA];
    __shared__ uint2 img[EPBA];
    int t = threadIdx.x;
    int base = blockIdx.x * EPBA;
    int cnt = min(EPBA, E - base);
    lhist[t] = 0;
    __syncthreads();
    uint ps[EPBA / 256], pw[EPBA / 256];
    int pb[EPBA / 256];
#pragma unroll
    for (int k = 0; k < EPBA / 256; ++k) {
        int i = base + k * 256 + t;
        pb[k] = -1;
        if (i < E) {
            int d = dst[i];
            int bk = d >> 8;  // NPB=256
            pb[k] = bk;
            ps[k] = (uint)src[i] | ((uint)(d & 255) << 23);
            pw[k] = __float_as_uint(ew[i]);
            atomicAdd(&lhist[bk], 1);
        }
    }
    __syncthreads();
    int v = lhist[t];
    lscan[t] = v;
    __syncthreads();
    for (int off = 1; off < 256; off <<= 1) {
        int u = (t >= off) ? lscan[t - off] : 0;
        __syncthreads();
        lscan[t] += u;
        __syncthreads();
    }
    lcur[t] = lscan[t] - v;
    if (v > 0) gbase[t] = atomicAdd(&gcur[t], v);
    __syncthreads();
#pragma unroll
    for (int k = 0; k < EPBA / 256; ++k) {
        if (pb[k] >= 0) {
            int p = atomicAdd(&lcur[pb[k]], 1);
            img[p] = make_uint2(ps[k], pw[k]);
            lbk[p] = pb[k];
        }
    }
    __syncthreads();
    for (int i = t; i < cnt; i += 256) {
        int bk = lbk[i];
        stage[gbase[bk] + (i - (lscan[bk] - lhist[bk]))] = img[i];
    }
}

__global__ __launch_bounds__(256) void passB_k(
    const uint2* __restrict__ stage, const int* __restrict__ bkoff,
    int* __restrict__ rowptr, int* __restrict__ cursor,
    int2* __restrict__ adj, int N, int nbk) {
    __shared__ int lhist[256];
    __shared__ int lpre[256];
    __shared__ int lcur[256];
    __shared__ uint2 img[CAP];
    int t = threadIdx.x;
    int b = blockIdx.x;
    int nb0 = b * NPB;
    int nn = min(NPB, N - nb0);
    int ebase = bkoff[b];
    int ecnt = bkoff[b + 1] - ebase;
    lhist[t] = 0;
    __syncthreads();
    for (int i = t; i < ecnt; i += 256) {
        uint2 e = stage[ebase + i];
        atomicAdd(&lhist[(e.x >> 23) & 255], 1);
    }
    __syncthreads();
    int v = lhist[t];
    lpre[t] = v;
    __syncthreads();
    for (int off = 1; off < 256; off <<= 1) {
        int u = (t >= off) ? lpre[t - off] : 0;
        __syncthreads();
        lpre[t] += u;
        __syncthreads();
    }
    int myoff = lpre[t] - v;
    lcur[t] = myoff;
    if (t < nn) {
        rowptr[nb0 + t] = ebase + myoff;
        cursor[nb0 + t] = ebase + myoff;
    }
    if (b == nbk - 1 && t == 0) rowptr[N] = ebase + ecnt;
    __syncthreads();
    if (ecnt <= CAP) {
        for (int i = t; i < ecnt; i += 256) {
            uint2 e = stage[ebase + i];
            int p = atomicAdd(&lcur[(e.x >> 23) & 255], 1);
            img[p] = make_uint2(e.x & 0x7fffffu, e.y);
        }
        __syncthreads();
        for (int i = t; i < ecnt; i += 256) {
            uint2 e = img[i];
            adj[ebase + i] = make_int2((int)e.x, (int)e.y);
        }
    } else {
        for (int i = t; i < ecnt; i += 256) {
            uint2 e = stage[ebase + i];
            int dl = (e.x >> 23) & 255;
            int p = atomicAdd(&cursor[nb0 + dl], 1);
            adj[p] = make_int2((int)(e.x & 0x7fffffu), (int)e.y);
        }
    }
}

// ---------------- generic fallback path (N > 65536 only) ----------------

__global__ void histn_k(const int* __restrict__ dst, int* __restrict__ cnt, int E) {
    int i = blockIdx.x * blockDim.x + threadIdx.x;
    if (i < E) atomicAdd(&cnt[dst[i]], 1);
}

__global__ void partial_k(const int* __restrict__ cnt, int* __restrict__ bsum, int N) {
    int t = threadIdx.x, b = blockIdx.x;
    int base = b * 1024 + t * 4;
    int s = 0;
    if (base + 4 <= N) {
        int4 v = *(const int4*)(cnt + base);
        s = v.x + v.y + v.z + v.w;
    } else {
        for (int j = 0; j < 4; ++j)
            if (base + j < N) s += cnt[base + j];
    }
    __shared__ int sm[256];
    sm[t] = s;
    __syncthreads();
    for (int off = 128; off > 0; off >>= 1) {
        if (t < off) sm[t] += sm[t + off];
        __syncthreads();
    }
    if (t == 0) bsum[b] = sm[0];
}

__global__ void scanb_k(const int* __restrict__ bsum, int* __restrict__ boff,
                        int* __restrict__ rowptr, int nb, int N) {
    int t = threadIdx.x;
    int v = (t < nb) ? bsum[t] : 0;
    __shared__ int sm[256];
    sm[t] = v;
    __syncthreads();
    for (int off = 1; off < 256; off <<= 1) {
        int u = (t >= off) ? sm[t - off] : 0;
        __syncthreads();
        sm[t] += u;
        __syncthreads();
    }
    if (t < nb) boff[t] = sm[t] - v;
    if (t == 255) rowptr[N] = sm[255];
}

__global__ void rowfill_k(const int* __restrict__ cnt, const int* __restrict__ boff,
                          int* __restrict__ rowptr, int* __restrict__ cursor, int N) {
    int t = threadIdx.x, b = blockIdx.x;
    int base = b * 1024 + t * 4;
    int c0 = 0, c1 = 0, c2 = 0, c3 = 0;
    if (base + 4 <= N) {
        int4 v = *(const int4*)(cnt + base);
        c0 = v.x; c1 = v.y; c2 = v.z; c3 = v.w;
    } else {
        if (base + 0 < N) c0 = cnt[base + 0];
        if (base + 1 < N) c1 = cnt[base + 1];
        if (base + 2 < N) c2 = cnt[base + 2];
        if (base + 3 < N) c3 = cnt[base + 3];
    }
    int s = c0 + c1 + c2 + c3;
    __shared__ int sm[256];
    sm[t] = s;
    __syncthreads();
    for (int off = 1; off < 256; off <<= 1) {
        int u = (t >= off) ? sm[t - off] : 0;
        __syncthreads();
        sm[t] += u;
        __syncthreads();
    }
    int run = boff[b] + sm[t] - s;
    if (base + 0 < N) { rowptr[base + 0] = run; cursor[base + 0] = run; run += c0; }
    if (base + 1 < N) { rowptr[base + 1] = run; cursor[base + 1] = run; run += c1; }
    if (base + 2 < N) { rowptr[base + 2] = run; cursor[base + 2] = run; run += c2; }
    if (base + 3 < N) { rowptr[base + 3] = run; cursor[base + 3] = run; run += c3; }
}

__global__ void fill_k(const int* __restrict__ src, const int* __restrict__ dst,
                       const float* __restrict__ ew, int* __restrict__ cursor,
                       int2* __restrict__ adj, int E) {
    int i = blockIdx.x * blockDim.x + threadIdx.x;
    if (i < E) {
        int p = atomicAdd(&cursor[dst[i]], 1);
        int2 e;
        e.x = src[i];
        e.y = __float_as_int(ew[i]);
        adj[p] = e;
    }
}

// ---- fused aggregation + MFMA: one block per 16-row strip (R15 scheme) ----
// Phase 1 (4 waves): wave w aggregates nodes w, w+4, w+8, w+12 (uint4 gather,
//   4 edge-slot groups x 16 col-lanes), stages mean'd bf16 row into LDS.
//   Self-term (layer 2) loaded by g==0 ONLY (group butterfly sums 4 groups).
// Phase 2 (wave 0): MFMA A-frags from LDS, B from Wt; epilogue per layer.

__device__ __forceinline__ float gelu_exact(float v) {
    return 0.5f * v * (1.0f + erff(v * 0.70710678118654752440f));
}

template <int SELF>  // 0: layer1 -> bf16 out ; 1: layer2 (+residual+LN+GELU) -> f32 out
__global__ __launch_bounds__(256) void aggmm_k(
    const uint4* __restrict__ xin4, const int* __restrict__ rowptr,
    const int2* __restrict__ adj, const ushort* __restrict__ Wt,
    const float* __restrict__ bl, const float* __restrict__ gamma,
    const float* __restrict__ beta, ushort* __restrict__ outb,
    float* __restrict__ outf, int N) {
    __shared__ __align__(16) ushort rows[16][136];
    __shared__ float wbs[16];
    int t = threadIdx.x;
    int wv = t >> 6;
    int lane = t & 63;
    int row0 = blockIdx.x << 4;
    int g = lane >> 4, c = lane & 15;

#define FMA8(V, W)                                                        \
    do {                                                                  \
        a0 += (W) * bf2f((V).x & 0xffffu); a1 += (W) * bf2f((V).x >> 16); \
        a2 += (W) * bf2f((V).y & 0xffffu); a3 += (W) * bf2f((V).y >> 16); \
        a4 += (W) * bf2f((V).z & 0xffffu); a5 += (W) * bf2f((V).z >> 16); \
        a6 += (W) * bf2f((V).w & 0xffffu); a7 += (W) * bf2f((V).w >> 16); \
    } while (0)

    for (int q = 0; q < 4; ++q) {
        int i = wv + q * 4;  // node slot 0..15
        int node = row0 + i;
        float a0 = 0.f, a1 = 0.f, a2 = 0.f, a3 = 0.f;
        float a4 = 0.f, a5 = 0.f, a6 = 0.f, a7 = 0.f, ws = 0.f;
        int lo = 0, hi = 0;
        if (node < N) {
            lo = rowptr[node];
            hi = rowptr[node + 1];
            if (SELF && g == 0) {  // self-loop once (butterfly sums 4 groups)
                uint4 v = xin4[(size_t)node * 16 + c];
                a0 = bf2f(v.x & 0xffffu); a1 = bf2f(v.x >> 16);
                a2 = bf2f(v.y & 0xffffu); a3 = bf2f(v.y >> 16);
                a4 = bf2f(v.z & 0xffffu); a5 = bf2f(v.z >> 16);
                a6 = bf2f(v.w & 0xffffu); a7 = bf2f(v.w >> 16);
            }
        }
        for (int base = lo; base < hi; base += 64) {
            int p = base + lane;
            int sidx = 0; float wv2 = 0.f;
            if (p < hi) {
                int2 e = adj[p];
                sidx = e.x;
                wv2 = __int_as_float(e.y);
            }
            ws += wv2;
            int cnt = min(hi - base, 64);
            int j = 0;
            for (; j + 16 <= cnt; j += 16) {
                int s0 = __shfl(sidx, j + g),     s1 = __shfl(sidx, j + 4 + g);
                int s2 = __shfl(sidx, j + 8 + g), s3 = __shfl(sidx, j + 12 + g);
                float w0 = __shfl(wv2, j + g),     w1 = __shfl(wv2, j + 4 + g);
                float w2 = __shfl(wv2, j + 8 + g), w3 = __shfl(wv2, j + 12 + g);
                uint4 v0 = xin4[(size_t)s0 * 16 + c];
                uint4 v1 = xin4[(size_t)s1 * 16 + c];
                uint4 v2 = xin4[(size_t)s2 * 16 + c];
                uint4 v3 = xin4[(size_t)s3 * 16 + c];
                FMA8(v0, w0); FMA8(v1, w1); FMA8(v2, w2); FMA8(v3, w3);
            }
            for (; j < cnt; j += 4) {
                // phantom slots (j+g >= cnt) carry sidx=0, wv2=0 -> harmless
                int s0 = __shfl(sidx, j + g);
                float w0 = __shfl(wv2, j + g);
                uint4 v0 = xin4[(size_t)s0 * 16 + c];
                FMA8(v0, w0);
            }
        }
        // combine 4 edge-slot groups (butterfly leaves sum in all lanes)
        a0 += __shfl_xor(a0, 16); a0 += __shfl_xor(a0, 32);
        a1 += __shfl_xor(a1, 16); a1 += __shfl_xor(a1, 32);
        a2 += __shfl_xor(a2, 16); a2 += __shfl_xor(a2, 32);
        a3 += __shfl_xor(a3, 16); a3 += __shfl_xor(a3, 32);
        a4 += __shfl_xor(a4, 16); a4 += __shfl_xor(a4, 32);
        a5 += __shfl_xor(a5, 16); a5 += __shfl_xor(a5, 32);
        a6 += __shfl_xor(a6, 16); a6 += __shfl_xor(a6, 32);
        a7 += __shfl_xor(a7, 16); a7 += __shfl_xor(a7, 32);
        ws += __shfl_xor(ws, 1);
        ws += __shfl_xor(ws, 2);
        ws += __shfl_xor(ws, 4);
        ws += __shfl_xor(ws, 8);
        ws += __shfl_xor(ws, 16);
        ws += __shfl_xor(ws, 32);
        int deg = hi - lo;
        float inv, wb;
        if (SELF) {
            inv = 1.0f / (float)(deg + 1);
            wb = (ws + 1.0f) * inv;
        } else {
            float dd = fmaxf((float)deg, 1.0f);
            inv = 1.0f / dd;
            wb = ws / dd;
        }
        if (g == 0) {
            uint4 o;
            o.x = f2bf(a0 * inv) | (f2bf(a1 * inv) << 16);
            o.y = f2bf(a2 * inv) | (f2bf(a3 * inv) << 16);
            o.z = f2bf(a4 * inv) | (f2bf(a5 * inv) << 16);
            o.w = f2bf(a6 * inv) | (f2bf(a7 * inv) << 16);
            *reinterpret_cast<uint4*>(&rows[i][c * 8]) = o;
            if (c == 0) wbs[i] = wb;
        }
    }
#undef FMA8
    __syncthreads();
    if (wv != 0) return;

    // wave 0: MFMA over the strip
    int kg = g << 3;
    bf16x8 af[4];
#pragma unroll
    for (int kc = 0; kc < 4; ++kc)
        af[kc] = *(const bf16x8*)&rows[c][kc * 32 + kg];

    f32x4 acc[8];
#pragma unroll
    for (int nt = 0; nt < 8; ++nt) {
        f32x4 a = {0.f, 0.f, 0.f, 0.f};
#pragma unroll
        for (int kc = 0; kc < 4; ++kc) {
            bf16x8 bf = *(const bf16x8*)(Wt + (size_t)(nt * 16 + c) * DF + kc * 32 + kg);
            a = __builtin_amdgcn_mfma_f32_16x16x32_bf16(af[kc], bf, a, 0, 0, 0);
        }
        acc[nt] = a;
    }

    const ushort* xin_s = (const ushort*)xin4;
#pragma unroll
    for (int r = 0; r < 4; ++r) {
        int i = g * 4 + r;
        int R = row0 + i;
        if (R >= N) continue;
        float wb = wbs[i];
        if (!SELF) {
#pragma unroll
            for (int nt = 0; nt < 8; ++nt) {
                int col = nt * 16 + c;
                outb[(size_t)R * DF + col] = (ushort)f2bf(acc[nt][r] + bl[col] * wb);
            }
        } else {
            float pre[8];
            float s = 0.f;
#pragma unroll
            for (int nt = 0; nt < 8; ++nt) {
                int col = nt * 16 + c;
                pre[nt] = acc[nt][r] + bl[col] * wb + bf2f(xin_s[(size_t)R * DF + col]);
                s += pre[nt];
            }
            s += __shfl_xor(s, 1);
            s += __shfl_xor(s, 2);
            s += __shfl_xor(s, 4);
            s += __shfl_xor(s, 8);
            float mu = s * (1.0f / 128.0f);
            float vs = 0.f;
#pragma unroll
            for (int nt = 0; nt < 8; ++nt) {
                float d = pre[nt] - mu;
                vs += d * d;
            }
            vs += __shfl_xor(vs, 1);
            vs += __shfl_xor(vs, 2);
            vs += __shfl_xor(vs, 4);
            vs += __shfl_xor(vs, 8);
            float rstd = rsqrtf(vs * (1.0f / 128.0f) + 1e-5f);
#pragma unroll
            for (int nt = 0; nt < 8; ++nt) {
                int col = nt * 16 + c;
                float y = (pre[nt] - mu) * rstd * gamma[col] + beta[col];
                outf[(size_t)R * DF + col] = gelu_exact(y);
            }
        }
    }
}

// ---------------- launch ----------------

extern "C" void kernel_launch(void* const* d_in, const int* in_sizes, int n_in,
                              void* d_out, int out_size, void* d_ws, size_t ws_size,
                              hipStream_t stream) {
    const float* x     = (const float*)d_in[0];
    const int*   ei    = (const int*)d_in[1];
    const float* ew    = (const float*)d_in[2];
    const float* Wl1   = (const float*)d_in[3];
    const float* bl1   = (const float*)d_in[4];
    const float* Wl2   = (const float*)d_in[5];
    const float* bl2   = (const float*)d_in[6];
    const float* gamma = (const float*)d_in[7];
    const float* beta  = (const float*)d_in[8];
    float* out = (float*)d_out;

    int N = in_sizes[0] / DF;
    int E = in_sizes[2];
    const int* src = ei;
    const int* dst = ei + E;

    char* ws = (char*)d_ws;
    size_t off = 0;
    auto alloc = [&](size_t bytes) -> void* {
        void* p = ws + off;
        off += (bytes + 255) & ~(size_t)255;
        return p;
    };
    int histB = (E + EPB - 1) / EPB;
    int*    rowptr  = (int*)alloc((size_t)(N + 1) * 4);
    int*    cursor  = (int*)alloc((size_t)N * 4);
    int*    bhist   = (int*)alloc((size_t)histB * 256 * 4);
    int*    bkoff   = (int*)alloc(1040);
    int*    gcur    = (int*)alloc(1024);
    int*    bsum    = (int*)alloc(1024);
    int*    boff    = (int*)alloc(1024);
    int2*   adj     = (int2*)alloc((size_t)E * 8);
    uint2*  stage   = (uint2*)alloc((size_t)E * 8);
    uint*   xb      = (uint*)alloc((size_t)N * DF * 2);
    ushort* x1b     = (ushort*)alloc((size_t)N * DF * 2);
    uint*   Wt1     = (uint*)alloc((size_t)DF * DF * 2);
    uint*   Wt2     = (uint*)alloc((size_t)DF * DF * 2);
    int*    cnt     = (int*)alloc((size_t)N * 4);  // fallback path only

    int nbk = (N + NPB - 1) / NPB;
    int n4 = N * DF / 4;
    int cvtxB = (n4 + 255) / 256;

    if (nbk <= 256) {
        hipLaunchKernelGGL(prep_k, dim3(cvtxB + 64 + histB), dim3(256), 0, stream,
                           x, xb, n4, Wl1, Wl2, Wt1, Wt2, dst, bhist, E, cvtxB);
        hipLaunchKernelGGL(bscan_k, dim3(1), dim3(256), 0, stream, bhist, histB, bkoff, gcur);
        int aB = (E + EPBA - 1) / EPBA;
        hipLaunchKernelGGL(passA_k, dim3(aB), dim3(256), 0, stream, src, dst, ew, gcur, stage, E);
        hipLaunchKernelGGL(passB_k, dim3(nbk), dim3(256), 0, stream,
                           stage, bkoff, rowptr, cursor, adj, N, nbk);
    } else {  // generic fallback (not taken for this problem size)
        hipMemsetAsync(cnt, 0, (size_t)N * 4, stream);
        hipLaunchKernelGGL(prep_k, dim3(cvtxB + 64), dim3(256), 0, stream,
                           x, xb, n4, Wl1, Wl2, Wt1, Wt2, dst, bhist, 0, cvtxB);
        int eb = (E + 255) / 256;
        hipLaunchKernelGGL(histn_k, dim3(eb), dim3(256), 0, stream, dst, cnt, E);
        int nb_scan = (N + 1023) / 1024;
        hipLaunchKernelGGL(partial_k, dim3(nb_scan), dim3(256), 0, stream, cnt, bsum, N);
        hipLaunchKernelGGL(scanb_k, dim3(1), dim3(256), 0, stream, bsum, boff, rowptr, nb_scan, N);
        hipLaunchKernelGGL(rowfill_k, dim3(nb_scan), dim3(256), 0, stream, cnt, boff, rowptr, cursor, N);
        hipLaunchKernelGGL(fill_k, dim3(eb), dim3(256), 0, stream, src, dst, ew, cursor, adj, E);
    }

    int nstrips = (N + 15) / 16;
    hipLaunchKernelGGL(aggmm_k<0>, dim3(nstrips), dim3(256), 0, stream,
                       (const uint4*)xb, rowptr, adj, (const ushort*)Wt1, bl1,
                       gamma, beta, x1b, (float*)nullptr, N);
    hipLaunchKernelGGL(aggmm_k<1>, dim3(nstrips), dim3(256), 0, stream,
                       (const uint4*)x1b, rowptr, adj, (const ushort*)Wt2, bl2,
                       gamma, beta, (ushort*)nullptr, out, N);
}